// Round 1
// baseline (703.920 us; speedup 1.0000x reference)
//
#include <hip/hip_runtime.h>

// Quantized 2x conv pipeline via v_mfma_i32_16x16x64_i8 (HW-verified on gfx950).
// All scales are powers of two -> exact integer math: int8 operands, int32
// accumulators (|acc| < 2^21), float requant exact.
//
// Implicit-GEMM mapping per wave (16x16x64 i8 MFMA):
//   M = 16 rows   = output channels (10 real + 6 zero-pad)
//   N = 16 cols   = 16 consecutive output pixels along ow
//   K = 64/128    = one dword per (c,kh): bytes (kw0,kw1,kw2,0); pad dwords = 0
// A (weights):   lane l holds rows m=l&15, k-dwords d=4*(l>>4)+r (r=0..3/frag)
// B (activation):lane l holds col  n=l&15, same k-dword mapping; each dword is
//                an unaligned 4-byte window built as alignbyte(u1,u0,n&3).
// D: col = lane&15 (pixel), row = 4*(lane>>4)+reg (oc). Bias folded into C.
//
// ws layout:
//   [0    ..   64) : consts: [0]=1/s_in, [1]=(s_in*s_w1)/s_o1,
//                    [2]=(s_o1*s_w2)/s_o2, [3]=s_o2
//   [256  .. 1280) : wA1  [64 lanes][4 dwords]  (conv1 A-fragment table)
//   [1280 .. 1344) : b1i  (16 ints, zero-padded)
//   [2048 .. 4096) : wA2  [64 lanes][8 dwords]  (conv2 A-fragments, 2 frags)
//   [4096 .. 4160) : b2i  (16 ints, zero-padded)
//   [8192      .. ) : x_int8 [32][5][512][512]
//   [41951488  .. ) : yq_int8 [32][10][510][512] (row stride 512, padded)

#define XQ_OFF   8192
#define YQ_OFF   41951488ULL

typedef int v4i __attribute__((ext_vector_type(4)));

__device__ __forceinline__ float qclamp(float v) {
    return fminf(fmaxf(v, -128.0f), 127.0f);
}

__device__ __forceinline__ int alignb(int hi, int lo, int sh) {
#if __has_builtin(__builtin_amdgcn_alignbyte)
    return __builtin_amdgcn_alignbyte(hi, lo, sh);
#else
    return (int)((((unsigned long long)(unsigned)hi << 32) | (unsigned)lo) >> (8 * sh));
#endif
}

__global__ __launch_bounds__(256) void prep_kernel(
    const float* __restrict__ w1, const float* __restrict__ b1,
    const float* __restrict__ w2, const float* __restrict__ b2,
    const float* __restrict__ s_in, const float* __restrict__ s_w1,
    const float* __restrict__ s_o1, const float* __restrict__ s_w2,
    const float* __restrict__ s_o2,
    float* __restrict__ consts, int* __restrict__ wA1, int* __restrict__ b1i,
    int* __restrict__ wA2, int* __restrict__ b2i)
{
    int t = threadIdx.x;
    float si = s_in[0], sw1 = s_w1[0], so1 = s_o1[0], sw2 = s_w2[0], so2 = s_o2[0];
    if (t == 0) {
        consts[0] = 1.0f / si;
        consts[1] = (si * sw1) / so1;   // 2^-7, exact
        consts[2] = (so1 * sw2) / so2;  // 2^-7, exact
        consts[3] = so2;
    }
    // wA1: [64][4] dwords. entry (l, r): d = 4*(l>>4)+r, row m = l&15.
    {
        int l = t >> 2, r = t & 3;
        int g = l >> 4, m = l & 15;
        int d = 4 * g + r;
        int val = 0;
        if (d < 15 && m < 10) {
            int c = d / 3, kh = d % 3;
            const float* src = w1 + (((m * 5 + c) * 3 + kh) * 3);
            int q0 = (int)qclamp(rintf(src[0] / sw1));
            int q1 = (int)qclamp(rintf(src[1] / sw1));
            int q2 = (int)qclamp(rintf(src[2] / sw1));
            val = (q0 & 255) | ((q1 & 255) << 8) | ((q2 & 255) << 16);
        }
        wA1[t] = val;
    }
    // wA2: [64][8] dwords. entry (l, r): frag f=r>>2, d = f*16 + 4*(l>>4) + (r&3).
    for (int i = t; i < 512; i += 256) {
        int l = i >> 3, r = i & 7;
        int g = l >> 4, m = l & 15;
        int f = r >> 2;
        int d = f * 16 + 4 * g + (r & 3);
        int val = 0;
        if (d < 30 && m < 10) {
            int c = d / 3, kh = d % 3;
            const float* src = w2 + (((m * 10 + c) * 3 + kh) * 3);
            int q0 = (int)qclamp(rintf(src[0] / sw2));
            int q1 = (int)qclamp(rintf(src[1] / sw2));
            int q2 = (int)qclamp(rintf(src[2] / sw2));
            val = (q0 & 255) | ((q1 & 255) << 8) | ((q2 & 255) << 16);
        }
        wA2[i] = val;
    }
    if (t < 16) {
        b1i[t] = (t < 10) ? (int)qclamp(rintf(b1[t] / (si * sw1))) : 0;
        b2i[t] = (t < 10) ? (int)qclamp(rintf(b2[t] / (so1 * sw2))) : 0;
    }
}

__global__ __launch_bounds__(256) void quant_x_kernel(
    const float4* __restrict__ x, const float* __restrict__ consts,
    int* __restrict__ xq, int n4)
{
    int i = blockIdx.x * 256 + threadIdx.x;
    if (i >= n4) return;
    float inv = consts[0];
    float4 v = x[i];
    int q0 = (int)qclamp(rintf(v.x * inv));
    int q1 = (int)qclamp(rintf(v.y * inv));
    int q2 = (int)qclamp(rintf(v.z * inv));
    int q3 = (int)qclamp(rintf(v.w * inv));
    xq[i] = (q0 & 255) | ((q1 & 255) << 8) | ((q2 & 255) << 16) | (q3 << 24);
}

// conv1: xq [32][5][512][512] int8 -> MFMA -> requant -> yq [32][10][510][512pad]
// waves = 32 n * 32 owt * 17 ohc (30 oh-rows each) = 17408 -> 4352 blocks
__global__ __launch_bounds__(256) void conv1_mfma(
    const signed char* __restrict__ xq, const int* __restrict__ wA,
    const int* __restrict__ bi, const float* __restrict__ consts,
    signed char* __restrict__ yq)
{
    int lane = threadIdx.x & 63;
    int W = blockIdx.x * 4 + (threadIdx.x >> 6);
    int owt = W & 31;
    int rem = W >> 5;
    int ohc = rem % 17;
    int n = rem / 17;
    int g = lane >> 4, m = lane & 15;
    int ow0 = owt << 4;

    v4i a = ((const v4i*)wA)[lane];
    v4i cinit;
    #pragma unroll
    for (int r = 0; r < 4; ++r) cinit[r] = bi[4 * g + r];

    int koff[4];
    #pragma unroll
    for (int s = 0; s < 4; ++s) {
        int d = 4 * g + s;
        koff[s] = (d < 15) ? (d / 3) * 262144 + (d % 3) * 512 : 0;
    }
    int xoff = ow0 + (m & ~3);
    int sh = m & 3;
    int oh0 = ohc * 30;
    int base = n * (5 * 512 * 512) + oh0 * 512 + xoff;
    float cr1 = consts[1];
    bool owv = (ow0 + m) < 510;
    size_t sbase = (((size_t)(n * 10) * 510) + oh0) * 512 + ow0 + m;

    for (int i = 0; i < 30; ++i) {
        v4i b;
        #pragma unroll
        for (int s = 0; s < 4; ++s) {
            const int* p = (const int*)(xq + base + koff[s]);
            int u0 = p[0], u1 = p[1];
            b[s] = alignb(u1, u0, sh);
        }
        v4i acc = __builtin_amdgcn_mfma_i32_16x16x64_i8(a, b, cinit, 0, 0, 0);
        #pragma unroll
        for (int r = 0; r < 4; ++r) {
            int oc = 4 * g + r;
            if (oc < 10 && owv) {
                int q = (int)qclamp(rintf((float)acc[r] * cr1));
                yq[sbase + (size_t)oc * (510 * 512)] = (signed char)q;
            }
        }
        base += 512;
        sbase += 512;
    }
}

// conv2: yq [32][10][510][512pad] int8 -> 2x MFMA (K=128) -> out fp32 [32][10][508][508]
// waves = 32 n * 32 owt * 16 ohc (<=32 oh-rows each) = 16384 -> 4096 blocks
__global__ __launch_bounds__(256) void conv2_mfma(
    const signed char* __restrict__ yq, const int* __restrict__ wA,
    const int* __restrict__ bi, const float* __restrict__ consts,
    float* __restrict__ out)
{
    int lane = threadIdx.x & 63;
    int W = blockIdx.x * 4 + (threadIdx.x >> 6);
    int owt = W & 31;
    int ohc = (W >> 5) & 15;
    int n = W >> 9;
    int g = lane >> 4, m = lane & 15;
    int ow0 = owt << 4;

    const v4i* wA4 = (const v4i*)wA;
    v4i a0 = wA4[lane * 2 + 0];
    v4i a1 = wA4[lane * 2 + 1];
    v4i cinit;
    #pragma unroll
    for (int r = 0; r < 4; ++r) cinit[r] = bi[4 * g + r];

    int koff[8];
    #pragma unroll
    for (int s = 0; s < 8; ++s) {
        int d = (s >> 2) * 16 + 4 * g + (s & 3);
        koff[s] = (d < 30) ? (d / 3) * (510 * 512) + (d % 3) * 512 : 0;
    }
    int xoff = ow0 + (m & ~3);
    int sh = m & 3;
    int oh0 = ohc * 32;
    int base = n * (10 * 510 * 512) + oh0 * 512 + xoff;
    float cr2 = consts[2];
    float so  = consts[3];
    bool owv = (ow0 + m) < 508;
    size_t sbase = (((size_t)(n * 10) * 508) + oh0) * 508 + ow0 + m;
    int iters = (508 - oh0 < 32) ? (508 - oh0) : 32;

    for (int i = 0; i < iters; ++i) {
        v4i b0, b1v;
        #pragma unroll
        for (int s = 0; s < 4; ++s) {
            const int* p = (const int*)(yq + base + koff[s]);
            int u0 = p[0], u1 = p[1];
            b0[s] = alignb(u1, u0, sh);
        }
        #pragma unroll
        for (int s = 4; s < 8; ++s) {
            const int* p = (const int*)(yq + base + koff[s]);
            int u0 = p[0], u1 = p[1];
            b1v[s - 4] = alignb(u1, u0, sh);
        }
        v4i acc = __builtin_amdgcn_mfma_i32_16x16x64_i8(a0, b0, cinit, 0, 0, 0);
        acc = __builtin_amdgcn_mfma_i32_16x16x64_i8(a1, b1v, acc, 0, 0, 0);
        #pragma unroll
        for (int r = 0; r < 4; ++r) {
            int oc = 4 * g + r;
            if (oc < 10 && owv) {
                float v = qclamp(rintf((float)acc[r] * cr2)) * so;
                out[sbase + (size_t)oc * (508 * 508)] = v;
            }
        }
        base += 512;
        sbase += 508;
    }
}

extern "C" void kernel_launch(void* const* d_in, const int* in_sizes, int n_in,
                              void* d_out, int out_size, void* d_ws, size_t ws_size,
                              hipStream_t stream) {
    const float* x    = (const float*)d_in[0];
    const float* w1   = (const float*)d_in[1];
    const float* b1   = (const float*)d_in[2];
    const float* w2   = (const float*)d_in[3];
    const float* b2   = (const float*)d_in[4];
    const float* s_in = (const float*)d_in[5];
    const float* s_w1 = (const float*)d_in[6];
    const float* s_o1 = (const float*)d_in[7];
    const float* s_w2 = (const float*)d_in[8];
    const float* s_o2 = (const float*)d_in[9];

    char* ws = (char*)d_ws;
    float* consts = (float*)ws;                 // 16 floats
    int* wA1 = (int*)(ws + 256);                // 256 dwords
    int* b1i = (int*)(ws + 1280);               // 16 ints
    int* wA2 = (int*)(ws + 2048);               // 512 dwords
    int* b2i = (int*)(ws + 4096);               // 16 ints
    signed char* xqb = (signed char*)(ws + XQ_OFF);
    signed char* yqb = (signed char*)(ws + YQ_OFF);

    prep_kernel<<<1, 256, 0, stream>>>(w1, b1, w2, b2, s_in, s_w1, s_o1, s_w2, s_o2,
                                       consts, wA1, b1i, wA2, b2i);

    int n4 = 32 * 5 * 512 * 512 / 4;            // 10,485,760 float4 groups
    quant_x_kernel<<<(n4 + 255) / 256, 256, 0, stream>>>(
        (const float4*)x, consts, (int*)xqb, n4);

    // conv1: 32*32*17 = 17408 waves -> 4352 blocks of 4 waves
    conv1_mfma<<<4352, 256, 0, stream>>>(xqb, wA1, b1i, consts, yqb);

    // conv2: 32*32*16 = 16384 waves -> 4096 blocks of 4 waves
    conv2_mfma<<<4096, 256, 0, stream>>>(yqb, wA2, b2i, consts, (float*)d_out);
}

// Round 2
// 608.451 us; speedup vs baseline: 1.1569x; 1.1569x over previous
//
#include <hip/hip_runtime.h>

// Quantized 2x conv pipeline via v_mfma_i32_16x16x64_i8, LDS-staged activations.
// Exact integer math (power-of-two scales): int8 operands, int32 accumulators
// (|acc| < 2^21), float requant exact.
//
// Implicit-GEMM per wave (16x16x64 i8 MFMA):
//   M = 16 = output channels (10 real + 6 zero-pad rows of A)
//   N = 16 = consecutive output pixels along ow
//   K dwords = (c,kh) pairs, bytes (kw0,kw1,kw2,0); pad dwords zero in A.
// Slot map (verified bit-exact in prior round): MFMA f, lane group g=lane>>4,
// reg j: d = f*16 + 4g + j -> (c = d/3, kh = d%3).
//
// Block = 256 thr (4 waves), tile = 256 ow-pixels x 16 oh-rows, all channels.
// Rolling 4-row LDS buffer [slot][c][72 dwords]; per output row: stage 1 new
// input row (coalesced dword loads -> ds_write), barrier, compute, barrier.
// B fragments built from LDS: ds_read2_b32 + v_alignbyte (window at col&3).
//
// ws layout:
//   [0    ..   64) : consts: [0]=1/s_in, [1]=(s_in*s_w1)/s_o1,
//                    [2]=(s_o1*s_w2)/s_o2, [3]=s_o2
//   [256  .. 1280) : wA1 [64 lanes][4 dwords]
//   [1280 .. 1344) : b1i (16 ints, zero-padded)
//   [2048 .. 4096) : wA2 [64 lanes][8 dwords]
//   [4096 .. 4160) : b2i (16 ints, zero-padded)
//   [8192      .. ) : x_int8 [32][5][512][512]
//   [41951488  .. ) : yq_int8 [32][10][510][512] (row stride 512, padded)

#define XQ_OFF   8192
#define YQ_OFF   41951488ULL

typedef int v4i __attribute__((ext_vector_type(4)));

__device__ __forceinline__ float qclamp(float v) {
    return fminf(fmaxf(v, -128.0f), 127.0f);
}

__device__ __forceinline__ int alignb(int hi, int lo, int sh) {
#if __has_builtin(__builtin_amdgcn_alignbyte)
    return __builtin_amdgcn_alignbyte(hi, lo, sh);
#else
    return (int)((((unsigned long long)(unsigned)hi << 32) | (unsigned)lo) >> (8 * sh));
#endif
}

__global__ __launch_bounds__(256) void prep_kernel(
    const float* __restrict__ w1, const float* __restrict__ b1,
    const float* __restrict__ w2, const float* __restrict__ b2,
    const float* __restrict__ s_in, const float* __restrict__ s_w1,
    const float* __restrict__ s_o1, const float* __restrict__ s_w2,
    const float* __restrict__ s_o2,
    float* __restrict__ consts, int* __restrict__ wA1, int* __restrict__ b1i,
    int* __restrict__ wA2, int* __restrict__ b2i)
{
    int t = threadIdx.x;
    float si = s_in[0], sw1 = s_w1[0], so1 = s_o1[0], sw2 = s_w2[0], so2 = s_o2[0];
    if (t == 0) {
        consts[0] = 1.0f / si;
        consts[1] = (si * sw1) / so1;   // 2^-7, exact
        consts[2] = (so1 * sw2) / so2;  // 2^-7, exact
        consts[3] = so2;
    }
    // wA1: [64][4] dwords. entry (l, r): d = 4*(l>>4)+r, row m = l&15.
    {
        int l = t >> 2, r = t & 3;
        int g = l >> 4, m = l & 15;
        int d = 4 * g + r;
        int val = 0;
        if (d < 15 && m < 10) {
            int c = d / 3, kh = d % 3;
            const float* src = w1 + (((m * 5 + c) * 3 + kh) * 3);
            int q0 = (int)qclamp(rintf(src[0] / sw1));
            int q1 = (int)qclamp(rintf(src[1] / sw1));
            int q2 = (int)qclamp(rintf(src[2] / sw1));
            val = (q0 & 255) | ((q1 & 255) << 8) | ((q2 & 255) << 16);
        }
        wA1[t] = val;
    }
    // wA2: [64][8] dwords. entry (l, r): f=r>>2, d = f*16 + 4*(l>>4) + (r&3).
    for (int i = t; i < 512; i += 256) {
        int l = i >> 3, r = i & 7;
        int g = l >> 4, m = l & 15;
        int f = r >> 2;
        int d = f * 16 + 4 * g + (r & 3);
        int val = 0;
        if (d < 30 && m < 10) {
            int c = d / 3, kh = d % 3;
            const float* src = w2 + (((m * 10 + c) * 3 + kh) * 3);
            int q0 = (int)qclamp(rintf(src[0] / sw2));
            int q1 = (int)qclamp(rintf(src[1] / sw2));
            int q2 = (int)qclamp(rintf(src[2] / sw2));
            val = (q0 & 255) | ((q1 & 255) << 8) | ((q2 & 255) << 16);
        }
        wA2[i] = val;
    }
    if (t < 16) {
        b1i[t] = (t < 10) ? (int)qclamp(rintf(b1[t] / (si * sw1))) : 0;
        b2i[t] = (t < 10) ? (int)qclamp(rintf(b2[t] / (so1 * sw2))) : 0;
    }
}

__global__ __launch_bounds__(256) void quant_x_kernel(
    const float4* __restrict__ x, const float* __restrict__ consts,
    int* __restrict__ xq, int n4)
{
    int i = blockIdx.x * 256 + threadIdx.x;
    if (i >= n4) return;
    float inv = consts[0];
    float4 v = x[i];
    int q0 = (int)qclamp(rintf(v.x * inv));
    int q1 = (int)qclamp(rintf(v.y * inv));
    int q2 = (int)qclamp(rintf(v.z * inv));
    int q3 = (int)qclamp(rintf(v.w * inv));
    xq[i] = (q0 & 255) | ((q1 & 255) << 8) | ((q2 & 255) << 16) | (q3 << 24);
}

// conv1: xq [32][5][512][512] int8 -> MFMA -> requant -> yq [32][10][510][512pad]
// grid: 32n x 2wt x 32rc = 2048 blocks of 256 threads.
__global__ __launch_bounds__(256) void conv1_mfma(
    const signed char* __restrict__ xq, const int* __restrict__ wA,
    const int* __restrict__ bi, const float* __restrict__ consts,
    signed char* __restrict__ yq)
{
    int tid = threadIdx.x;
    int b = blockIdx.x;
    int rc = b & 31, wt = (b >> 5) & 1, n = b >> 6;
    int oh0 = rc * 16;
    int rows = 510 - oh0; if (rows > 16) rows = 16;
    int ow0 = wt << 8;

    __shared__ int lds[4 * 5 * 72];   // 4 row-slots x 5 c x 288B

    int lane = tid & 63;
    int w = tid >> 6;
    int g = lane >> 4, m = lane & 15;
    int sh = m & 3;
    int wcol = w * 64;

    v4i a = ((const v4i*)wA)[lane];
    v4i cinit;
    #pragma unroll
    for (int r = 0; r < 4; ++r) cinit[r] = bi[4 * g + r];

    int khv[4], inv[4];
    #pragma unroll
    for (int j = 0; j < 4; ++j) {
        int d = 4 * g + j;
        int c = 0, kh = 0;
        if (d < 15) { c = d / 3; kh = d % 3; }
        khv[j] = kh;
        inv[j] = c * 72 + ((wcol + (m & ~3)) >> 2);
    }

    const signed char* src = xq + (size_t)n * (5 * 512 * 512);
    float cr1 = consts[1];

    // stage row ih into slot ih&3: 5 c x 68 dwords (272B) from byte ow0
    #define STAGE1(ih_) do {                                                 \
        int ih = (ih_);                                                      \
        int slot = ih & 3;                                                   \
        _Pragma("unroll")                                                    \
        for (int pass = 0; pass < 2; ++pass) {                               \
            int j = tid + pass * 256;                                        \
            if (j < 340) {                                                   \
                int c = j / 68;                                              \
                int off = j - c * 68;                                        \
                int col = ow0 + (off << 2);                                  \
                if (col > 508) col = 508;                                    \
                lds[(slot * 5 + c) * 72 + off] =                             \
                    *(const int*)(src + c * 262144 + ih * 512 + col);        \
            }                                                                \
        }                                                                    \
    } while (0)

    STAGE1(oh0);
    STAGE1(oh0 + 1);

    for (int i = 0; i < rows; ++i) {
        int oh = oh0 + i;
        STAGE1(oh + 2);
        __syncthreads();

        int rsl[4];
        #pragma unroll
        for (int j = 0; j < 4; ++j)
            rsl[j] = ((oh + khv[j]) & 3) * 360 + inv[j];

        size_t sb = (size_t)(n * 10) * (510 * 512) + (size_t)oh * 512
                  + (size_t)(ow0 + wcol + m);
        #pragma unroll
        for (int nt = 0; nt < 4; ++nt) {
            v4i bb;
            #pragma unroll
            for (int j = 0; j < 4; ++j) {
                const int* p = lds + rsl[j] + nt * 4;
                int u0 = p[0], u1 = p[1];
                bb[j] = alignb(u1, u0, sh);
            }
            v4i acc = __builtin_amdgcn_mfma_i32_16x16x64_i8(a, bb, cinit, 0, 0, 0);
            int colv = ow0 + wcol + nt * 16 + m;
            bool cv = colv < 510;
            #pragma unroll
            for (int r = 0; r < 4; ++r) {
                int oc = 4 * g + r;
                if (oc < 10 && cv) {
                    int q = (int)qclamp(rintf((float)acc[r] * cr1));
                    yq[sb + nt * 16 + (size_t)oc * (510 * 512)] = (signed char)q;
                }
            }
        }
        __syncthreads();
    }
    #undef STAGE1
}

// conv2: yq [32][10][510][512pad] int8 -> 2x MFMA (K=128) -> out fp32
// grid: 32n x 2wt x 32rc = 2048 blocks of 256 threads.
__global__ __launch_bounds__(256) void conv2_mfma(
    const signed char* __restrict__ yq, const int* __restrict__ wA,
    const int* __restrict__ bi, const float* __restrict__ consts,
    float* __restrict__ out)
{
    int tid = threadIdx.x;
    int b = blockIdx.x;
    int rc = b & 31, wt = (b >> 5) & 1, n = b >> 6;
    int oh0 = rc * 16;
    int rows = 508 - oh0; if (rows > 16) rows = 16;
    int ow0 = wt << 8;

    __shared__ int lds[4 * 10 * 72];  // 4 row-slots x 10 c x 288B = 11.5KB

    int lane = tid & 63;
    int w = tid >> 6;
    int g = lane >> 4, m = lane & 15;
    int sh = m & 3;
    int wcol = w * 64;

    const v4i* wA4 = (const v4i*)wA;
    v4i a0 = wA4[lane * 2 + 0];
    v4i a1 = wA4[lane * 2 + 1];
    v4i cinit;
    #pragma unroll
    for (int r = 0; r < 4; ++r) cinit[r] = bi[4 * g + r];

    int khv[8], inv[8];
    #pragma unroll
    for (int s = 0; s < 8; ++s) {
        int d = (s >> 2) * 16 + 4 * g + (s & 3);
        int c = 0, kh = 0;
        if (d < 30) { c = d / 3; kh = d % 3; }
        khv[s] = kh;
        inv[s] = c * 72 + ((wcol + (m & ~3)) >> 2);
    }

    const signed char* src = yq + (size_t)n * (10 * 510 * 512);
    float cr2 = consts[2];
    float so  = consts[3];

    // stage row ih into slot ih&3: 10 c x 68 dwords (272B) from byte ow0
    #define STAGE2(ih_) do {                                                 \
        int ih = (ih_);                                                      \
        int slot = ih & 3;                                                   \
        _Pragma("unroll")                                                    \
        for (int pass = 0; pass < 3; ++pass) {                               \
            int j = tid + pass * 256;                                        \
            if (j < 680) {                                                   \
                int c = j / 68;                                              \
                int off = j - c * 68;                                        \
                int col = ow0 + (off << 2);                                  \
                if (col > 508) col = 508;                                    \
                lds[(slot * 10 + c) * 72 + off] =                            \
                    *(const int*)(src + c * (510 * 512) + ih * 512 + col);   \
            }                                                                \
        }                                                                    \
    } while (0)

    STAGE2(oh0);
    STAGE2(oh0 + 1);

    for (int i = 0; i < rows; ++i) {
        int oh = oh0 + i;
        STAGE2(oh + 2);
        __syncthreads();

        int rsl[8];
        #pragma unroll
        for (int s = 0; s < 8; ++s)
            rsl[s] = ((oh + khv[s]) & 3) * 720 + inv[s];

        size_t ob = (size_t)(n * 10) * (508 * 508) + (size_t)oh * 508;
        #pragma unroll
        for (int nt = 0; nt < 4; ++nt) {
            v4i bb0, bb1;
            #pragma unroll
            for (int s = 0; s < 4; ++s) {
                const int* p = lds + rsl[s] + nt * 4;
                int u0 = p[0], u1 = p[1];
                bb0[s] = alignb(u1, u0, sh);
            }
            #pragma unroll
            for (int s = 4; s < 8; ++s) {
                const int* p = lds + rsl[s] + nt * 4;
                int u0 = p[0], u1 = p[1];
                bb1[s - 4] = alignb(u1, u0, sh);
            }
            v4i acc = __builtin_amdgcn_mfma_i32_16x16x64_i8(a0, bb0, cinit, 0, 0, 0);
            acc = __builtin_amdgcn_mfma_i32_16x16x64_i8(a1, bb1, acc, 0, 0, 0);
            int colv = ow0 + wcol + nt * 16 + m;
            bool cv = colv < 508;
            #pragma unroll
            for (int r = 0; r < 4; ++r) {
                int oc = 4 * g + r;
                if (oc < 10 && cv) {
                    float v = qclamp(rintf((float)acc[r] * cr2)) * so;
                    out[ob + (size_t)oc * (508 * 508) + colv] = v;
                }
            }
        }
        __syncthreads();
    }
    #undef STAGE2
}

extern "C" void kernel_launch(void* const* d_in, const int* in_sizes, int n_in,
                              void* d_out, int out_size, void* d_ws, size_t ws_size,
                              hipStream_t stream) {
    const float* x    = (const float*)d_in[0];
    const float* w1   = (const float*)d_in[1];
    const float* b1   = (const float*)d_in[2];
    const float* w2   = (const float*)d_in[3];
    const float* b2   = (const float*)d_in[4];
    const float* s_in = (const float*)d_in[5];
    const float* s_w1 = (const float*)d_in[6];
    const float* s_o1 = (const float*)d_in[7];
    const float* s_w2 = (const float*)d_in[8];
    const float* s_o2 = (const float*)d_in[9];

    char* ws = (char*)d_ws;
    float* consts = (float*)ws;                 // 16 floats
    int* wA1 = (int*)(ws + 256);                // 256 dwords
    int* b1i = (int*)(ws + 1280);               // 16 ints
    int* wA2 = (int*)(ws + 2048);               // 512 dwords
    int* b2i = (int*)(ws + 4096);               // 16 ints
    signed char* xqb = (signed char*)(ws + XQ_OFF);
    signed char* yqb = (signed char*)(ws + YQ_OFF);

    prep_kernel<<<1, 256, 0, stream>>>(w1, b1, w2, b2, s_in, s_w1, s_o1, s_w2, s_o2,
                                       consts, wA1, b1i, wA2, b2i);

    int n4 = 32 * 5 * 512 * 512 / 4;            // 10,485,760 float4 groups
    quant_x_kernel<<<(n4 + 255) / 256, 256, 0, stream>>>(
        (const float4*)x, consts, (int*)xqb, n4);

    // conv1: 32n x 2wt x 32rc = 2048 blocks
    conv1_mfma<<<2048, 256, 0, stream>>>(xqb, wA1, b1i, consts, yqb);

    // conv2: 32n x 2wt x 32rc = 2048 blocks
    conv2_mfma<<<2048, 256, 0, stream>>>(yqb, wA2, b2i, consts, (float*)d_out);
}

// Round 3
// 588.300 us; speedup vs baseline: 1.1965x; 1.0343x over previous
//
#include <hip/hip_runtime.h>

// Quantized 2x conv pipeline via v_mfma_i32_16x16x64_i8, LDS-staged activations,
// 4-row phases with T14 async-STAGE split (issue loads early / ds_write late),
// ONE barrier per phase, quantization of x fused into conv1's staging.
// Exact integer math (power-of-two scales): int8 operands, int32 accumulators
// (|acc| < 2^21), float requant exact.
//
// Implicit-GEMM per wave (16x16x64 i8 MFMA):
//   M = 16 = output channels (10 real + 6 zero-pad rows of A)
//   N = 16 = consecutive output pixels along ow
//   K dwords = (c,kh) pairs, bytes (kw0,kw1,kw2,0); pad dwords zero in A.
// Slot map (bit-exact verified rounds 1-2): MFMA f, lane group g=lane>>4,
// reg j: d = f*16 + 4g + j -> (c = d/3, kh = d%3).
//
// Block = 256 thr (4 waves), tile = 256 ow-pixels x 32 oh-rows, all channels.
// Rolling 10-slot LDS row buffer; phase k (4 output rows oh..oh+3):
//   issue global loads for input rows oh+6..oh+9 (into regs)
//   compute rows oh..oh+3 from LDS slots (rows oh..oh+5)   <- hides load latency
//   ds_write regs -> slots ((oh+6..oh+9)-oh0) mod 10  (disjoint from reads)
//   __syncthreads()                                    <- single barrier/phase
//
// ws layout:
//   [0    ..   64) : consts: [0]=1/s_in, [1]=(s_in*s_w1)/s_o1,
//                    [2]=(s_o1*s_w2)/s_o2, [3]=s_o2
//   [256  .. 1280) : wA1 [64 lanes][4 dwords]
//   [1280 .. 1344) : b1i (16 ints, zero-padded)
//   [2048 .. 4096) : wA2 [64 lanes][8 dwords]
//   [4096 .. 4160) : b2i (16 ints, zero-padded)
//   [41951488  .. ) : yq_int8 [32][10][510][512] (row stride 512, padded)

#define YQ_OFF   41951488ULL

typedef int v4i __attribute__((ext_vector_type(4)));

__device__ __forceinline__ float qclamp(float v) {
    return fminf(fmaxf(v, -128.0f), 127.0f);
}

__device__ __forceinline__ int alignb(int hi, int lo, int sh) {
#if __has_builtin(__builtin_amdgcn_alignbyte)
    return __builtin_amdgcn_alignbyte(hi, lo, sh);
#else
    return (int)((((unsigned long long)(unsigned)hi << 32) | (unsigned)lo) >> (8 * sh));
#endif
}

__device__ __forceinline__ int pack4(float4 v, float s) {
    int q0 = (int)qclamp(rintf(v.x * s));
    int q1 = (int)qclamp(rintf(v.y * s));
    int q2 = (int)qclamp(rintf(v.z * s));
    int q3 = (int)qclamp(rintf(v.w * s));
    return (q0 & 255) | ((q1 & 255) << 8) | ((q2 & 255) << 16) | (q3 << 24);
}

__global__ __launch_bounds__(256) void prep_kernel(
    const float* __restrict__ w1, const float* __restrict__ b1,
    const float* __restrict__ w2, const float* __restrict__ b2,
    const float* __restrict__ s_in, const float* __restrict__ s_w1,
    const float* __restrict__ s_o1, const float* __restrict__ s_w2,
    const float* __restrict__ s_o2,
    float* __restrict__ consts, int* __restrict__ wA1, int* __restrict__ b1i,
    int* __restrict__ wA2, int* __restrict__ b2i)
{
    int t = threadIdx.x;
    float si = s_in[0], sw1 = s_w1[0], so1 = s_o1[0], sw2 = s_w2[0], so2 = s_o2[0];
    if (t == 0) {
        consts[0] = 1.0f / si;
        consts[1] = (si * sw1) / so1;   // 2^-7, exact
        consts[2] = (so1 * sw2) / so2;  // 2^-7, exact
        consts[3] = so2;
    }
    // wA1: [64][4] dwords. entry (l, r): d = 4*(l>>4)+r, row m = l&15.
    {
        int l = t >> 2, r = t & 3;
        int g = l >> 4, m = l & 15;
        int d = 4 * g + r;
        int val = 0;
        if (d < 15 && m < 10) {
            int c = d / 3, kh = d % 3;
            const float* src = w1 + (((m * 5 + c) * 3 + kh) * 3);
            int q0 = (int)qclamp(rintf(src[0] / sw1));
            int q1 = (int)qclamp(rintf(src[1] / sw1));
            int q2 = (int)qclamp(rintf(src[2] / sw1));
            val = (q0 & 255) | ((q1 & 255) << 8) | ((q2 & 255) << 16);
        }
        wA1[t] = val;
    }
    // wA2: [64][8] dwords. entry (l, r): f=r>>2, d = f*16 + 4*(l>>4) + (r&3).
    for (int i = t; i < 512; i += 256) {
        int l = i >> 3, r = i & 7;
        int g = l >> 4, m = l & 15;
        int f = r >> 2;
        int d = f * 16 + 4 * g + (r & 3);
        int val = 0;
        if (d < 30 && m < 10) {
            int c = d / 3, kh = d % 3;
            const float* src = w2 + (((m * 10 + c) * 3 + kh) * 3);
            int q0 = (int)qclamp(rintf(src[0] / sw2));
            int q1 = (int)qclamp(rintf(src[1] / sw2));
            int q2 = (int)qclamp(rintf(src[2] / sw2));
            val = (q0 & 255) | ((q1 & 255) << 8) | ((q2 & 255) << 16);
        }
        wA2[i] = val;
    }
    if (t < 16) {
        b1i[t] = (t < 10) ? (int)qclamp(rintf(b1[t] / (si * sw1))) : 0;
        b2i[t] = (t < 10) ? (int)qclamp(rintf(b2[t] / (so1 * sw2))) : 0;
    }
}

// conv1 (+fused input quant): x fp32 [32][5][512][512] -> int8 windows in LDS
// -> MFMA -> requant -> yq [32][10][510][512pad]
// grid: 32n x 2wt x 16rc = 1024 blocks of 256 threads.
__global__ __launch_bounds__(256) void conv1_mfma(
    const float* __restrict__ x, const int* __restrict__ wA,
    const int* __restrict__ bi, const float* __restrict__ consts,
    signed char* __restrict__ yq)
{
    int tid = threadIdx.x;
    int b = blockIdx.x;
    int rc = b & 15, wt = (b >> 4) & 1, n = b >> 5;
    int oh0 = rc * 32;
    int ow0 = wt << 8;

    __shared__ int lds[10 * 360];   // 10 row-slots x 5 c x 72 dwords = 14.4 KB

    int lane = tid & 63;
    int w = tid >> 6;
    int g = lane >> 4, m = lane & 15;
    int sh = m & 3;
    int wcol = w * 64;

    v4i a = ((const v4i*)wA)[lane];
    v4i cinit;
    #pragma unroll
    for (int r = 0; r < 4; ++r) cinit[r] = bi[4 * g + r];

    int khv[4], invv[4];
    #pragma unroll
    for (int j = 0; j < 4; ++j) {
        int d = 4 * g + j;
        int c = 0, kh = 0;
        if (d < 15) { c = d / 3; kh = d % 3; }
        khv[j] = kh;
        invv[j] = c * 72 + ((wcol + (m & ~3)) >> 2);
    }

    float qs  = consts[0];
    float cr1 = consts[1];
    const float* xb = x + (size_t)n * (5 * 512 * 512);

    // stage-item precompute: 4 rows x 5 c x 68 dwords = 1360 items, 6 passes
    int rl_[6], lb_[6], go_[6]; bool va_[6];
    #pragma unroll
    for (int i = 0; i < 6; ++i) {
        int j = tid + i * 256;
        va_[i] = j < 1360;
        int jj = va_[i] ? j : 0;
        int rl = jj / 340, rem = jj - rl * 340;
        int c = rem / 68, off = rem - c * 68;
        int col = ow0 + off * 4; if (col > 508) col = 508;
        rl_[i] = rl;
        lb_[i] = c * 72 + off;
        go_[i] = c * 262144 + col;          // float index; add ih*512 per phase
    }

    // prologue: input rows oh0..oh0+5 -> slots 0..5 (6 x 340 = 2040 items)
    #pragma unroll
    for (int i = 0; i < 8; ++i) {
        int j = tid + i * 256;
        if (j < 2040) {
            int rl = j / 340, rem = j - rl * 340;
            int c = rem / 68, off = rem - c * 68;
            int col = ow0 + off * 4; if (col > 508) col = 508;
            int ih = oh0 + rl; if (ih > 511) ih = 511;
            float4 v = *(const float4*)(xb + (size_t)c * 262144 + ih * 512 + col);
            lds[rl * 360 + c * 72 + off] = pack4(v, qs);
        }
    }
    __syncthreads();

    int s_off = 0;
    for (int k = 0; k < 8; ++k) {
        int oh = oh0 + 4 * k;
        bool do_stage = k < 7;

        // T14: issue next-phase loads (input rows oh+6..oh+9)
        float4 sreg[6];
        if (do_stage) {
            int ihb = oh + 6;
            #pragma unroll
            for (int i = 0; i < 6; ++i) {
                int ih = ihb + rl_[i]; if (ih > 511) ih = 511;
                if (va_[i])
                    sreg[i] = *(const float4*)(xb + go_[i] + (size_t)ih * 512);
            }
        }

        // compute output rows oh..oh+3 from LDS (rows oh..oh+5)
        #pragma unroll
        for (int r = 0; r < 4; ++r) {
            int ohr = oh + r;
            if (ohr >= 510) break;          // block-uniform
            int sofr = s_off + r;
            int rsl[4];
            #pragma unroll
            for (int j = 0; j < 4; ++j) {
                int t = sofr + khv[j]; if (t >= 10) t -= 10;
                rsl[j] = t * 360 + invv[j];
            }
            size_t sb = (size_t)(n * 10) * (510 * 512) + (size_t)ohr * 512
                      + (size_t)(ow0 + wcol + m);
            #pragma unroll
            for (int nt = 0; nt < 4; ++nt) {
                v4i bb;
                #pragma unroll
                for (int j = 0; j < 4; ++j) {
                    const int* p = lds + rsl[j] + nt * 4;
                    int u0 = p[0], u1 = p[1];
                    bb[j] = alignb(u1, u0, sh);
                }
                v4i acc = __builtin_amdgcn_mfma_i32_16x16x64_i8(a, bb, cinit, 0, 0, 0);
                int colv = ow0 + wcol + nt * 16 + m;
                bool cv = colv < 510;
                #pragma unroll
                for (int rr = 0; rr < 4; ++rr) {
                    int oc = 4 * g + rr;
                    if (oc < 10 && cv) {
                        int q = (int)qclamp(rintf((float)acc[rr] * cr1));
                        yq[sb + nt * 16 + (size_t)oc * (510 * 512)] = (signed char)q;
                    }
                }
            }
        }

        // late write: quantize landed regs -> slots of dead rows (disjoint)
        if (do_stage) {
            #pragma unroll
            for (int i = 0; i < 6; ++i) {
                if (va_[i]) {
                    int t = s_off + 6 + rl_[i]; if (t >= 10) t -= 10;
                    lds[t * 360 + lb_[i]] = pack4(sreg[i], qs);
                }
            }
        }
        __syncthreads();
        s_off += 4; if (s_off >= 10) s_off -= 10;
    }
}

// conv2: yq [32][10][510][512pad] int8 -> 2x MFMA (K=128) -> out fp32
// grid: 32n x 2wt x 16rc = 1024 blocks of 256 threads.
__global__ __launch_bounds__(256) void conv2_mfma(
    const signed char* __restrict__ yq, const int* __restrict__ wA,
    const int* __restrict__ bi, const float* __restrict__ consts,
    float* __restrict__ out)
{
    int tid = threadIdx.x;
    int b = blockIdx.x;
    int rc = b & 15, wt = (b >> 4) & 1, n = b >> 5;
    int oh0 = rc * 32;
    int ow0 = wt << 8;

    __shared__ int lds[10 * 720];   // 10 row-slots x 10 c x 72 dwords = 28.8 KB

    int lane = tid & 63;
    int w = tid >> 6;
    int g = lane >> 4, m = lane & 15;
    int sh = m & 3;
    int wcol = w * 64;

    const v4i* wA4 = (const v4i*)wA;
    v4i a0 = wA4[lane * 2 + 0];
    v4i a1 = wA4[lane * 2 + 1];
    v4i cinit;
    #pragma unroll
    for (int r = 0; r < 4; ++r) cinit[r] = bi[4 * g + r];

    int khv[8], invv[8];
    #pragma unroll
    for (int s = 0; s < 8; ++s) {
        int d = (s >> 2) * 16 + 4 * g + (s & 3);
        int c = 0, kh = 0;
        if (d < 30) { c = d / 3; kh = d % 3; }
        khv[s] = kh;
        invv[s] = c * 72 + ((wcol + (m & ~3)) >> 2);
    }

    const signed char* yb = yq + (size_t)n * (10 * 510 * 512);
    float cr2 = consts[2];
    float so  = consts[3];

    // stage-item precompute: 4 rows x 10 c x 68 dwords = 2720 items, 11 passes
    int rl_[11], lb_[11], go_[11]; bool va_[11];
    #pragma unroll
    for (int i = 0; i < 11; ++i) {
        int j = tid + i * 256;
        va_[i] = j < 2720;
        int jj = va_[i] ? j : 0;
        int rl = jj / 680, rem = jj - rl * 680;
        int c = rem / 68, off = rem - c * 68;
        int col = ow0 + off * 4; if (col > 508) col = 508;
        rl_[i] = rl;
        lb_[i] = c * 72 + off;
        go_[i] = c * 261120 + col;          // byte index; add ih*512 per phase
    }

    // prologue: input rows oh0..oh0+5 -> slots 0..5 (6 x 680 = 4080 items)
    #pragma unroll
    for (int i = 0; i < 16; ++i) {
        int j = tid + i * 256;
        if (j < 4080) {
            int rl = j / 680, rem = j - rl * 680;
            int c = rem / 68, off = rem - c * 68;
            int col = ow0 + off * 4; if (col > 508) col = 508;
            int ih = oh0 + rl; if (ih > 509) ih = 509;
            lds[rl * 720 + c * 72 + off] =
                *(const int*)(yb + (size_t)c * 261120 + (size_t)ih * 512 + col);
        }
    }
    __syncthreads();

    int valid = 508 - oh0; if (valid > 32) valid = 32;
    int nph = (valid + 3) >> 2;
    int s_off = 0;
    for (int k = 0; k < nph; ++k) {
        int oh = oh0 + 4 * k;
        bool do_stage = (k + 1) < nph;

        // T14: issue next-phase loads (input rows oh+6..oh+9)
        int sreg[11];
        if (do_stage) {
            int ihb = oh + 6;
            #pragma unroll
            for (int i = 0; i < 11; ++i) {
                int ih = ihb + rl_[i]; if (ih > 509) ih = 509;
                if (va_[i])
                    sreg[i] = *(const int*)(yb + go_[i] + (size_t)ih * 512);
            }
        }

        // compute output rows oh..oh+3 from LDS (rows oh..oh+5)
        #pragma unroll
        for (int r = 0; r < 4; ++r) {
            int ohr = oh + r;
            if (ohr >= 508) break;          // block-uniform
            int sofr = s_off + r;
            int rsl[8];
            #pragma unroll
            for (int s = 0; s < 8; ++s) {
                int t = sofr + khv[s]; if (t >= 10) t -= 10;
                rsl[s] = t * 720 + invv[s];
            }
            size_t ob = (size_t)(n * 10) * (508 * 508) + (size_t)ohr * 508;
            #pragma unroll
            for (int nt = 0; nt < 4; ++nt) {
                v4i bb0, bb1;
                #pragma unroll
                for (int s = 0; s < 4; ++s) {
                    const int* p = lds + rsl[s] + nt * 4;
                    int u0 = p[0], u1 = p[1];
                    bb0[s] = alignb(u1, u0, sh);
                }
                #pragma unroll
                for (int s = 4; s < 8; ++s) {
                    const int* p = lds + rsl[s] + nt * 4;
                    int u0 = p[0], u1 = p[1];
                    bb1[s - 4] = alignb(u1, u0, sh);
                }
                v4i acc = __builtin_amdgcn_mfma_i32_16x16x64_i8(a0, bb0, cinit, 0, 0, 0);
                acc = __builtin_amdgcn_mfma_i32_16x16x64_i8(a1, bb1, acc, 0, 0, 0);
                int colv = ow0 + wcol + nt * 16 + m;
                bool cv = colv < 508;
                #pragma unroll
                for (int rr = 0; rr < 4; ++rr) {
                    int oc = 4 * g + rr;
                    if (oc < 10 && cv) {
                        float v = qclamp(rintf((float)acc[rr] * cr2)) * so;
                        out[ob + (size_t)oc * (508 * 508) + colv] = v;
                    }
                }
            }
        }

        // late write: landed regs -> slots of dead rows (disjoint from reads)
        if (do_stage) {
            #pragma unroll
            for (int i = 0; i < 11; ++i) {
                if (va_[i]) {
                    int t = s_off + 6 + rl_[i]; if (t >= 10) t -= 10;
                    lds[t * 720 + lb_[i]] = sreg[i];
                }
            }
        }
        __syncthreads();
        s_off += 4; if (s_off >= 10) s_off -= 10;
    }
}

extern "C" void kernel_launch(void* const* d_in, const int* in_sizes, int n_in,
                              void* d_out, int out_size, void* d_ws, size_t ws_size,
                              hipStream_t stream) {
    const float* x    = (const float*)d_in[0];
    const float* w1   = (const float*)d_in[1];
    const float* b1   = (const float*)d_in[2];
    const float* w2   = (const float*)d_in[3];
    const float* b2   = (const float*)d_in[4];
    const float* s_in = (const float*)d_in[5];
    const float* s_w1 = (const float*)d_in[6];
    const float* s_o1 = (const float*)d_in[7];
    const float* s_w2 = (const float*)d_in[8];
    const float* s_o2 = (const float*)d_in[9];

    char* ws = (char*)d_ws;
    float* consts = (float*)ws;                 // 16 floats
    int* wA1 = (int*)(ws + 256);                // 256 dwords
    int* b1i = (int*)(ws + 1280);               // 16 ints
    int* wA2 = (int*)(ws + 2048);               // 512 dwords
    int* b2i = (int*)(ws + 4096);               // 16 ints
    signed char* yqb = (signed char*)(ws + YQ_OFF);

    prep_kernel<<<1, 256, 0, stream>>>(w1, b1, w2, b2, s_in, s_w1, s_o1, s_w2, s_o2,
                                       consts, wA1, b1i, wA2, b2i);

    // conv1 (+fused quant): 32n x 2wt x 16rc = 1024 blocks
    conv1_mfma<<<1024, 256, 0, stream>>>(x, wA1, b1i, consts, yqb);

    // conv2: 32n x 2wt x 16rc = 1024 blocks
    conv2_mfma<<<1024, 256, 0, stream>>>(yqb, wA2, b2i, consts, (float*)d_out);
}